// Round 6
// baseline (220.627 us; speedup 1.0000x reference)
//
#include <hip/hip_runtime.h>
#include <stdint.h>

typedef __bf16 bf16;
typedef __attribute__((ext_vector_type(4))) float f32x4;
typedef __attribute__((ext_vector_type(16))) float f32x16;
typedef __attribute__((ext_vector_type(4))) int i32x4;
typedef __attribute__((ext_vector_type(8))) __bf16 bf16x8;
typedef __attribute__((ext_vector_type(4))) __bf16 bf16x4;

#define NB 16      // batch
#define CH 512     // channels
#define HWS 1024   // H*W
#define NHEAD 8
#define DH 64
#define O3 1536    // 3*C
#define CPQ 136    // qkv C-restage pitch (bf16)
#define CPF 132    // proj C-restage pitch (fp32)
#define OPD 72     // flash epilogue staging pitch (bf16)

// async global->LDS, 16B per lane; LDS dest = wave-uniform base + lane*16
__device__ __forceinline__ void gload_lds16(const bf16* g, bf16* l) {
    __builtin_amdgcn_global_load_lds(
        (const __attribute__((address_space(1))) unsigned int*)g,
        (__attribute__((address_space(3))) unsigned int*)l,
        16, 0, 0);
}

// raw v_exp_f32 (2^x) via compiler-visible intrinsic
#if defined(__has_builtin) && __has_builtin(__builtin_amdgcn_exp2f)
__device__ __forceinline__ float fast_exp2(float x) { return __builtin_amdgcn_exp2f(x); }
#else
__device__ __forceinline__ float fast_exp2(float x) { return exp2f(x); }
#endif

// pack two f32 -> one u32 of two bf16 (RNE via scalar casts; compiler fuses pack)
__device__ __forceinline__ unsigned int pkbf(float a, float b) {
    unsigned short lo = __builtin_bit_cast(unsigned short, (bf16)a);
    unsigned short hi = __builtin_bit_cast(unsigned short, (bf16)b);
    return (unsigned int)lo | ((unsigned int)hi << 16);
}

// ---------------------------------------------------------------- prep: gn stats + weight cvt
__global__ void prep(const float* __restrict__ x, float* __restrict__ stats,
                     const float* __restrict__ wq, const float* __restrict__ wp,
                     bf16* __restrict__ wq_b, bf16* __restrict__ wp_b) {
    int bx = blockIdx.x;
    if (bx < 512) {                 // groupnorm stats: b*32+g
        int b = bx >> 5, g = bx & 31;
        const float4* p = (const float4*)(x + ((size_t)(b * CH + g * 16)) * HWS);
        float s = 0.f, ss = 0.f;
        for (int i = threadIdx.x; i < 4096; i += 256) {
            float4 v = p[i];
            s  += v.x + v.y + v.z + v.w;
            ss += v.x*v.x + v.y*v.y + v.z*v.z + v.w*v.w;
        }
        for (int off = 32; off; off >>= 1) {
            s  += __shfl_xor(s,  off, 64);
            ss += __shfl_xor(ss, off, 64);
        }
        __shared__ float red[8];
        int w = threadIdx.x >> 6;
        if ((threadIdx.x & 63) == 0) { red[w*2] = s; red[w*2+1] = ss; }
        __syncthreads();
        if (threadIdx.x == 0) {
            float S  = red[0] + red[2] + red[4] + red[6];
            float SS = red[1] + red[3] + red[5] + red[7];
            float mean = S * (1.f/16384.f);
            float var  = SS * (1.f/16384.f) - mean*mean;
            stats[bx*2]   = mean;
            stats[bx*2+1] = rsqrtf(var + 1e-5f);
        }
    } else {                        // weight fp32 -> bf16
        int i = (bx - 512) * 256 + threadIdx.x;
        if (i < O3*CH) wq_b[i] = (bf16)wq[i];
        else           wp_b[i - O3*CH] = (bf16)wp[i - O3*CH];
    }
}

// ---------------------------------------------------------------- normalize + transpose -> hT (16384,512) bf16
__global__ void gn_apply_t(const float* __restrict__ x, const float* __restrict__ stats,
                           const float* __restrict__ gamma, const float* __restrict__ beta,
                           bf16* __restrict__ hT) {
    __shared__ float tile[32][33];
    int bx = blockIdx.x;            // 16 * 16 * 32 = 8192 blocks
    int b = bx >> 9;
    int rem = bx & 511;
    int ct = rem >> 5, nt = rem & 31;
    int tx = threadIdx.x & 31, ty = threadIdx.x >> 5;   // ty 0..7
    #pragma unroll
    for (int r = 0; r < 4; ++r) {
        int c = ct*32 + ty + r*8;
        int n = nt*32 + tx;
        float v = x[((size_t)(b * CH + c)) * HWS + n];
        int g = c >> 4;
        float mean = stats[(b*32+g)*2], rstd = stats[(b*32+g)*2+1];
        tile[ty + r*8][tx] = (v - mean) * rstd * gamma[c] + beta[c];
    }
    __syncthreads();
    #pragma unroll
    for (int r = 0; r < 4; ++r) {
        int n = nt*32 + ty + r*8;
        int c = ct*32 + tx;
        hT[((size_t)(b * HWS + n)) * CH + c] = (bf16)tile[tx][ty + r*8];
    }
}

// ---------------------------------------------------------------- qkv GEMM + fused V-transpose (round-7)
__global__ __launch_bounds__(256, 3)
void qkv_gemm(const bf16* __restrict__ W, const bf16* __restrict__ hT,
              const float* __restrict__ bias, bf16* __restrict__ qkv,
              bf16* __restrict__ vT) {
    __shared__ __align__(16) bf16 SMEM[128*CPQ];   // 34816 B (staging uses 32 KB)
    bf16* As = SMEM;            // [128 o][64 k] swizzled, pitch 64
    bf16* Bs = SMEM + 8192;     // [128 bn][64 k]
    int bx = blockIdx.x;                 // 12 * 128 = 1536 blocks
    int po = bx >> 7, qo = bx & 127;     // qo low bits -> XCD locality on hT
    int obase = po*128, bnbase = qo*128;
    int tid = threadIdx.x;
    int lane = tid & 63, w = tid >> 6;
    int quad = lane >> 4, l15 = lane & 15;
    int wm = w >> 1, wn = w & 1;
    int x7 = l15 & 7;
    int srow = lane >> 3, spos = lane & 7;          // wave covers 8 rows x 8 chunks
    int sgc = (spos ^ srow) * 8;                    // swizzled source chunk (elements)

    f32x4 acc[4][4] = {};
    for (int k0 = 0; k0 < 512; k0 += 64) {
        #pragma unroll
        for (int r = 0; r < 4; ++r) {
            int rb = r*32 + w*8;                    // row-group base (multiple of 8)
            gload_lds16(W  + ((size_t)(obase  + rb + srow))*512 + k0 + sgc, &As[rb*64]);
            gload_lds16(hT + ((size_t)(bnbase + rb + srow))*512 + k0 + sgc, &Bs[rb*64]);
        }
        __syncthreads();                            // drains vmcnt -> tiles ready
        #pragma unroll
        for (int ks = 0; ks < 2; ++ks) {
            int ch = (ks*4 + quad) ^ x7;
            bf16x8 af[4], bfv[4];
            #pragma unroll
            for (int mt = 0; mt < 4; ++mt)
                af[mt] = *(const bf16x8*)(&As[(wm*64 + mt*16 + l15)*64 + ch*8]);
            #pragma unroll
            for (int nt = 0; nt < 4; ++nt)
                bfv[nt] = *(const bf16x8*)(&Bs[(wn*64 + nt*16 + l15)*64 + ch*8]);
            #pragma unroll
            for (int mt = 0; mt < 4; ++mt)
                #pragma unroll
                for (int nt = 0; nt < 4; ++nt)
                    acc[mt][nt] = __builtin_amdgcn_mfma_f32_16x16x32_bf16(af[mt], bfv[nt], acc[mt][nt], 0, 0, 0);
        }
        __syncthreads();
    }

    // ---- epilogue: bias, V-direct stores, C restage for Q/K (round-4 exact)
    bf16* Cs = SMEM;                 // [128 bn][CPQ]
    int b = bnbase >> 10;
    int nbase = bnbase & 1023;
    #pragma unroll
    for (int mt = 0; mt < 4; ++mt) {
        int o0 = obase + wm*64 + mt*16 + quad*4;
        float4 bb = *(const float4*)(bias + o0);
        int c192 = o0 % 192;
        bool isV = (c192 >= 128);
        int h = o0 / 192;
        int d0 = c192 - 128;
        #pragma unroll
        for (int nt = 0; nt < 4; ++nt) {
            int bn_l = wn*64 + nt*16 + l15;
            bf16x4 v;
            v[0] = (bf16)(acc[mt][nt][0] + bb.x);
            v[1] = (bf16)(acc[mt][nt][1] + bb.y);
            v[2] = (bf16)(acc[mt][nt][2] + bb.z);
            v[3] = (bf16)(acc[mt][nt][3] + bb.w);
            *(bf16x4*)(&Cs[bn_l*CPQ + (o0 - obase)]) = v;
            if (isV) {
                int key = nbase + bn_l;
                size_t vb_ = ((size_t)((b*8 + h)*64 + d0)) * HWS + key;
                vT[vb_]          = v[0];
                vT[vb_ + HWS]    = v[1];
                vT[vb_ + 2*HWS]  = v[2];
                vT[vb_ + 3*HWS]  = v[3];
            }
        }
    }
    __syncthreads();
    #pragma unroll
    for (int p = 0; p < 8; ++p) {
        int bn_l = p*16 + (tid >> 4);
        int o8 = (tid & 15) * 8;
        if ((obase + o8) % 192 < 128) {
            uint4 v = *(const uint4*)(&Cs[bn_l*CPQ + o8]);
            *(uint4*)(qkv + ((size_t)(bnbase + bn_l)) * O3 + obase + o8) = v;
        }
    }
}

// ---------------------------------------------------------------- flash attention (v11)
// m214-architecture port: 32x32x16 MFMAs, swapped QK^T, fully in-register softmax.
//  - QK: z = mfma32(K-frag, Q-frag): D[m=key(regs)][n=q(lane&31)] — each lane holds
//    the P-row slice for ONE q. exp + row-sum are lane-local (no cross-lane in loop).
//  - P-frags for PV assembled IN REGISTERS: cvt/pack adjacent-key pairs to u32,
//    one lane^32 word exchange (__shfl_xor 32) + cndmask by half — the per-kt P LDS
//    round-trip (16 b64 wr + 8 b128 rd + lgkm + conflicts) is deleted.
//  - PV: acc = mfma32(V^T-frag[d][key] from Vs, P-frag[q][key]): D[m=d(regs)][n=q].
//    Linv is a per-lane scalar (q = lane&31): no broadcast.
//  - MFMA count/wave-kt: 16x 32x32x16 (was 64x 16x16x32) — ~60% fewer matrix slots.
//  - K/V staging identical to v10 (dbuf DMA, pre-swizzled source, 1 barrier/kt).
// 32 q/wave, 4 waves = 128 q/block; grid 1024 (g=bx&127 XCD-local, qt=bx>>7).
// LDS 50 KB -> 3 blocks/CU (12 waves).
__global__ __launch_bounds__(256, 3)
void flash_attn(const bf16* __restrict__ qkv, const bf16* __restrict__ vT,
                bf16* __restrict__ A2) {
    __shared__ __align__(16) bf16 Ks[2][64*64];    // 16 KB
    __shared__ __align__(16) bf16 Vs[2][64*64];    // 16 KB  [d 64][key 64] swizzled
    __shared__ __align__(16) bf16 Ps[4][32*OPD];   // 18 KB, per-wave epilogue staging
    int bx = blockIdx.x;                 // 1024
    int g = bx & 127, qt = bx >> 7;
    int b = g >> 3, h = g & 7;
    int tid = threadIdx.x, lane = tid & 63, w = tid >> 6;   // w 0..3
    int l31 = lane & 31, hi = lane >> 5;
    bool hib = (hi != 0);
    int x7l = l31 & 7;
    int srow = lane >> 3, spos = lane & 7;
    int sgc = (spos ^ srow) * 8;         // pre-swizzled source chunk for linear LDS dest
    const float kLog2 = 0.04419417382415922f * 1.44269504088896341f; // 512^-0.5 * log2(e)

    // Q-frags (B operand): Q[q = l31][d = seg*16 + hi*8 + j], pre-scaled
    bf16x8 aq[4];
    {
        int qrow = qt*128 + w*32 + l31;
        const bf16* qb = qkv + ((size_t)(b * HWS + qrow)) * O3 + h*192 + hi*8;
        #pragma unroll
        for (int seg = 0; seg < 4; ++seg) {
            aq[seg] = *(const bf16x8*)(qb + seg*16);
            #pragma unroll
            for (int j = 0; j < 8; ++j)
                aq[seg][j] = (bf16)((float)aq[seg][j] * kLog2);
        }
    }

    // staging: wave w covers rows w*16..w*16+15 of the 64-row tile (2 DMAs each)
    const bf16* kg = qkv + ((size_t)(b*HWS + w*16 + srow))*O3 + h*192 + 64 + sgc;
    const bf16* vg = vT  + ((size_t)(g*DH  + w*16 + srow))*HWS + sgc;

    gload_lds16(kg,                  &Ks[0][(w*16)*64]);
    gload_lds16(kg + (size_t)8*O3,   &Ks[0][(w*16 + 8)*64]);
    gload_lds16(vg,                  &Vs[0][(w*16)*64]);
    gload_lds16(vg + (size_t)8*HWS,  &Vs[0][(w*16 + 8)*64]);

    f32x16 acc[2] = {};                  // D[m=d regs][n=q lane]; db = d/32
    f32x4 L4 = {};                       // lane-local partial row sums (q = l31)
    __syncthreads();                     // drains vmcnt: tile 0 ready

    for (int kt = 0; kt < 16; ++kt) {
        int cur = kt & 1;
        if (kt < 15) {                   // prefetch kt+1 (async DMA)
            gload_lds16(kg + (size_t)((kt+1)*64)*O3,     &Ks[cur^1][(w*16)*64]);
            gload_lds16(kg + (size_t)((kt+1)*64 + 8)*O3, &Ks[cur^1][(w*16 + 8)*64]);
            gload_lds16(vg + (kt+1)*64,                  &Vs[cur^1][(w*16)*64]);
            gload_lds16(vg + (size_t)8*HWS + (kt+1)*64,  &Vs[cur^1][(w*16 + 8)*64]);
        }
        const bf16* Kc = &Ks[cur][0];
        const bf16* Vc = &Vs[cur][0];

        bf16x8 pa[4];                    // P-frags: B[q = l31][key = kseg*16 + hi*8 + j]
        #pragma unroll
        for (int kb = 0; kb < 2; ++kb) {
            // S^T block: keys kb*32..+31 x q 0..31 over d=64
            f32x16 z = {};
            #pragma unroll
            for (int seg = 0; seg < 4; ++seg) {
                bf16x8 ak = *(const bf16x8*)(&Kc[(kb*32 + l31)*64 + (((seg*2 + hi) ^ x7l)*8)]);
                z = __builtin_amdgcn_mfma_f32_32x32x16_bf16(ak, aq[seg], z, 0, 0, 0);
            }
            // exp (lane-local row slice: key = kb*32 + (r&3)+8*(r>>2)+4*hi)
            float e[16];
            #pragma unroll
            for (int r = 0; r < 16; ++r) {
                e[r] = fast_exp2(z[r]);
                L4[r & 3] += e[r];
            }
            // pack adjacent-key pairs: word i = keys kb*32 + (i>>1)*8 + (i&1)*2 + 4*hi
            unsigned int w8[8];
            #pragma unroll
            for (int i = 0; i < 8; ++i)
                w8[i] = pkbf(e[2*i], e[2*i + 1]);
            // lane^32 exchange: partner half holds keys offset by 4
            unsigned int p0 = __shfl_xor((int)w8[0], 32, 64);
            unsigned int p1 = __shfl_xor((int)w8[1], 32, 64);
            unsigned int p2 = __shfl_xor((int)w8[2], 32, 64);
            unsigned int p3 = __shfl_xor((int)w8[3], 32, 64);
            unsigned int p4 = __shfl_xor((int)w8[4], 32, 64);
            unsigned int p5 = __shfl_xor((int)w8[5], 32, 64);
            unsigned int p6 = __shfl_xor((int)w8[6], 32, 64);
            unsigned int p7 = __shfl_xor((int)w8[7], 32, 64);
            i32x4 f0, f1;
            f0[0] = (int)(hib ? p2 : w8[0]);  // keys kseg0: hi*8 + {0,1}
            f0[1] = (int)(hib ? p3 : w8[1]);  //            hi*8 + {2,3}
            f0[2] = (int)(hib ? w8[2] : p0);  //            hi*8 + {4,5}
            f0[3] = (int)(hib ? w8[3] : p1);  //            hi*8 + {6,7}
            f1[0] = (int)(hib ? p6 : w8[4]);
            f1[1] = (int)(hib ? p7 : w8[5]);
            f1[2] = (int)(hib ? w8[6] : p4);
            f1[3] = (int)(hib ? w8[7] : p5);
            pa[kb*2 + 0] = __builtin_bit_cast(bf16x8, f0);
            pa[kb*2 + 1] = __builtin_bit_cast(bf16x8, f1);
        }

        // PV: acc[db] += V^T[d][key] x P[q][key] over 4 key-segs
        #pragma unroll
        for (int db = 0; db < 2; ++db)
            #pragma unroll
            for (int ks = 0; ks < 4; ++ks) {
                bf16x8 av = *(const bf16x8*)(&Vc[(db*32 + l31)*64 + (((ks*2 + hi) ^ x7l)*8)]);
                acc[db] = __builtin_amdgcn_mfma_f32_32x32x16_bf16(av, pa[ks], acc[db], 0, 0, 0);
            }
        __syncthreads();   // all waves done with buf[cur]; prefetch drained
    }

    // row sum: lane-local partials + the other half's keys
    float Lf = (L4[0] + L4[1]) + (L4[2] + L4[3]);
    Lf += __shfl_xor(Lf, 32, 64);
    float Linv = 1.f / Lf;

    // epilogue: acc[db][r] = out[d = db*32 + (r&3)+8*(r>>2)+4*hi][q = l31]
    // stage per-wave [32 q][64 d] bf16 (pitch OPD), then b128 coalesced store
    bf16* Psw = &Ps[w][0];
    #pragma unroll
    for (int db = 0; db < 2; ++db)
        #pragma unroll
        for (int i = 0; i < 8; ++i) {
            int d = db*32 + (i >> 1)*8 + (i & 1)*2 + 4*hi;
            unsigned int wv = pkbf(acc[db][2*i] * Linv, acc[db][2*i + 1] * Linv);
            *(unsigned int*)(&Psw[l31*OPD + d]) = wv;
        }

    int bp = g & 15;          // output batch (reference's head-major quirk)
    int hp = g >> 4;          // output head slot
    #pragma unroll
    for (int cc = 0; cc < 4; ++cc) {
        int idx = cc*64 + lane;
        int q = idx >> 3, dcc = idx & 7;
        uint4 v = *(const uint4*)(&Psw[q*OPD + dcc*8]);
        size_t oidx = ((size_t)(bp * HWS + qt*128 + w*32 + q)) * CH + hp*64 + dcc*8;
        *(uint4*)(A2 + oidx) = v;
    }
}

// ---------------------------------------------------------------- proj GEMM + bias + residual (round-7)
__global__ __launch_bounds__(256, 3)
void proj_gemm(const bf16* __restrict__ A2, const bf16* __restrict__ Wp,
               const float* __restrict__ bias, const float* __restrict__ x,
               float* __restrict__ out) {
    __shared__ __align__(16) bf16 SMEM[16896];     // 33792 B (staging 32 KB)
    bf16* As = SMEM;            // [128 bn][64 k] swizzled, pitch 64
    bf16* Bs = SMEM + 8192;     // [128 o][64 k]
    int bx = blockIdx.x;                 // 512
    int po = bx >> 7, qo = bx & 127;
    int obase = po*128, bnbase = qo*128;
    int tid = threadIdx.x;
    int lane = tid & 63, w = tid >> 6;
    int quad = lane >> 4, l15 = lane & 15;
    int wm = w >> 1, wn = w & 1;
    int x7 = l15 & 7;
    int srow = lane >> 3, spos = lane & 7;
    int sgc = (spos ^ srow) * 8;

    f32x4 acc[4][4] = {};
    for (int k0 = 0; k0 < 512; k0 += 64) {
        #pragma unroll
        for (int r = 0; r < 4; ++r) {
            int rb = r*32 + w*8;
            gload_lds16(A2 + ((size_t)(bnbase + rb + srow))*512 + k0 + sgc, &As[rb*64]);
            gload_lds16(Wp + ((size_t)(obase  + rb + srow))*512 + k0 + sgc, &Bs[rb*64]);
        }
        __syncthreads();
        #pragma unroll
        for (int ks = 0; ks < 2; ++ks) {
            int ch = (ks*4 + quad) ^ x7;
            bf16x8 af[4], bfv[4];
            #pragma unroll
            for (int mt = 0; mt < 4; ++mt)
                af[mt] = *(const bf16x8*)(&As[(wm*64 + mt*16 + l15)*64 + ch*8]);
            #pragma unroll
            for (int nt = 0; nt < 4; ++nt)
                bfv[nt] = *(const bf16x8*)(&Bs[(wn*64 + nt*16 + l15)*64 + ch*8]);
            #pragma unroll
            for (int mt = 0; mt < 4; ++mt)
                #pragma unroll
                for (int nt = 0; nt < 4; ++nt)
                    acc[mt][nt] = __builtin_amdgcn_mfma_f32_16x16x32_bf16(af[mt], bfv[nt], acc[mt][nt], 0, 0, 0);
        }
        __syncthreads();
    }

    // epilogue (round-4 exact): bn = bnbase + wm*64 + mt*16 + quad*4 + r, o = obase + wn*64 + nt*16 + l15
    float* Cf = (float*)SMEM;        // [64 bn][CPF] fp32 per half-pass
    int bb = bnbase >> 10;
    int nbase = bnbase & 1023;
    #pragma unroll
    for (int hh = 0; hh < 2; ++hh) {
        if (wm == hh) {
            #pragma unroll
            for (int mt = 0; mt < 4; ++mt)
                #pragma unroll
                for (int nt = 0; nt < 4; ++nt)
                    #pragma unroll
                    for (int r = 0; r < 4; ++r)
                        Cf[(mt*16 + quad*4 + r)*CPF + wn*64 + nt*16 + l15] = acc[mt][nt][r];
        }
        __syncthreads();
        #pragma unroll
        for (int p = 0; p < 4; ++p) {
            int ol = p*32 + (tid >> 3);
            int nl0 = (tid & 7) * 8;
            int o = obase + ol;
            float bv = bias[o];
            #pragma unroll
            for (int jj = 0; jj < 2; ++jj) {
                int nl = nl0 + jj*4;
                size_t idx = ((size_t)(bb * CH + o)) * HWS + nbase + hh*64 + nl;
                float4 xr = *(const float4*)(x + idx);
                float4 res;
                res.x = Cf[(nl+0)*CPF + ol] + bv + xr.x;
                res.y = Cf[(nl+1)*CPF + ol] + bv + xr.y;
                res.z = Cf[(nl+2)*CPF + ol] + bv + xr.z;
                res.w = Cf[(nl+3)*CPF + ol] + bv + xr.w;
                *(float4*)(out + idx) = res;
            }
        }
        __syncthreads();
    }
}

// ---------------------------------------------------------------- launch
extern "C" void kernel_launch(void* const* d_in, const int* in_sizes, int n_in,
                              void* d_out, int out_size, void* d_ws, size_t ws_size,
                              hipStream_t stream) {
    const float* x      = (const float*)d_in[0];
    const float* gamma  = (const float*)d_in[1];
    const float* beta   = (const float*)d_in[2];
    const float* w_qkv  = (const float*)d_in[3];
    const float* b_qkv  = (const float*)d_in[4];
    const float* w_proj = (const float*)d_in[5];
    const float* b_proj = (const float*)d_in[6];
    float* out = (float*)d_out;

    char* ws = (char*)d_ws;
    float* stats = (float*)(ws + 0);                       //   4 KB
    bf16*  wq_b  = (bf16*)(ws + 4096);                     // 1.5 MB
    bf16*  wp_b  = (bf16*)(ws + 1576960);                  // 0.5 MB
    bf16*  hT    = (bf16*)(ws + 2101248);                  // 16 MB (aliased by A2 later)
    bf16*  qkv   = (bf16*)(ws + 18878464);                 // 48 MB (V slots unused)
    bf16*  vT    = (bf16*)(ws + 69210112);                 // 16 MB
    bf16*  A2    = hT;                                     // reuse: hT dead after qkv_gemm

    prep       <<<4608, 256, 0, stream>>>(x, stats, w_qkv, w_proj, wq_b, wp_b);
    gn_apply_t <<<8192, 256, 0, stream>>>(x, stats, gamma, beta, hT);
    qkv_gemm   <<<1536, 256, 0, stream>>>(wq_b, hT, b_qkv, qkv, vT);
    flash_attn <<<1024, 256, 0, stream>>>(qkv, vT, A2);
    proj_gemm  <<<512,  256, 0, stream>>>(A2, wp_b, b_proj, x, out);
}

// Round 7
// 198.382 us; speedup vs baseline: 1.1121x; 1.1121x over previous
//
#include <hip/hip_runtime.h>
#include <stdint.h>

typedef __bf16 bf16;
typedef __attribute__((ext_vector_type(4))) float f32x4;
typedef __attribute__((ext_vector_type(16))) float f32x16;
typedef __attribute__((ext_vector_type(4))) int i32x4;
typedef __attribute__((ext_vector_type(8))) __bf16 bf16x8;
typedef __attribute__((ext_vector_type(4))) __bf16 bf16x4;

#define NB 16      // batch
#define CH 512     // channels
#define HWS 1024   // H*W
#define NHEAD 8
#define DH 64
#define O3 1536    // 3*C
#define CPQ 136    // qkv C-restage pitch (bf16)
#define CPF 132    // proj C-restage pitch (fp32)
#define OPD 72     // flash epilogue staging pitch (bf16)

// async global->LDS, 16B per lane; LDS dest = wave-uniform base + lane*16
__device__ __forceinline__ void gload_lds16(const bf16* g, bf16* l) {
    __builtin_amdgcn_global_load_lds(
        (const __attribute__((address_space(1))) unsigned int*)g,
        (__attribute__((address_space(3))) unsigned int*)l,
        16, 0, 0);
}

// raw v_exp_f32 (2^x) via compiler-visible intrinsic
#if defined(__has_builtin) && __has_builtin(__builtin_amdgcn_exp2f)
__device__ __forceinline__ float fast_exp2(float x) { return __builtin_amdgcn_exp2f(x); }
#else
__device__ __forceinline__ float fast_exp2(float x) { return exp2f(x); }
#endif

// pack two f32 -> one u32 of two bf16 (RNE via scalar casts)
__device__ __forceinline__ unsigned int pkbf(float a, float b) {
    unsigned short lo = __builtin_bit_cast(unsigned short, (bf16)a);
    unsigned short hi = __builtin_bit_cast(unsigned short, (bf16)b);
    return (unsigned int)lo | ((unsigned int)hi << 16);
}

// ---------------------------------------------------------------- prep: gn stats + weight cvt
__global__ void prep(const float* __restrict__ x, float* __restrict__ stats,
                     const float* __restrict__ wq, const float* __restrict__ wp,
                     bf16* __restrict__ wq_b, bf16* __restrict__ wp_b) {
    int bx = blockIdx.x;
    if (bx < 512) {                 // groupnorm stats: b*32+g
        int b = bx >> 5, g = bx & 31;
        const float4* p = (const float4*)(x + ((size_t)(b * CH + g * 16)) * HWS);
        float s = 0.f, ss = 0.f;
        for (int i = threadIdx.x; i < 4096; i += 256) {
            float4 v = p[i];
            s  += v.x + v.y + v.z + v.w;
            ss += v.x*v.x + v.y*v.y + v.z*v.z + v.w*v.w;
        }
        for (int off = 32; off; off >>= 1) {
            s  += __shfl_xor(s,  off, 64);
            ss += __shfl_xor(ss, off, 64);
        }
        __shared__ float red[8];
        int w = threadIdx.x >> 6;
        if ((threadIdx.x & 63) == 0) { red[w*2] = s; red[w*2+1] = ss; }
        __syncthreads();
        if (threadIdx.x == 0) {
            float S  = red[0] + red[2] + red[4] + red[6];
            float SS = red[1] + red[3] + red[5] + red[7];
            float mean = S * (1.f/16384.f);
            float var  = SS * (1.f/16384.f) - mean*mean;
            stats[bx*2]   = mean;
            stats[bx*2+1] = rsqrtf(var + 1e-5f);
        }
    } else {                        // weight fp32 -> bf16
        int i = (bx - 512) * 256 + threadIdx.x;
        if (i < O3*CH) wq_b[i] = (bf16)wq[i];
        else           wp_b[i - O3*CH] = (bf16)wp[i - O3*CH];
    }
}

// ---------------------------------------------------------------- normalize + transpose -> hT (16384,512) bf16
__global__ void gn_apply_t(const float* __restrict__ x, const float* __restrict__ stats,
                           const float* __restrict__ gamma, const float* __restrict__ beta,
                           bf16* __restrict__ hT) {
    __shared__ float tile[32][33];
    int bx = blockIdx.x;            // 16 * 16 * 32 = 8192 blocks
    int b = bx >> 9;
    int rem = bx & 511;
    int ct = rem >> 5, nt = rem & 31;
    int tx = threadIdx.x & 31, ty = threadIdx.x >> 5;   // ty 0..7
    #pragma unroll
    for (int r = 0; r < 4; ++r) {
        int c = ct*32 + ty + r*8;
        int n = nt*32 + tx;
        float v = x[((size_t)(b * CH + c)) * HWS + n];
        int g = c >> 4;
        float mean = stats[(b*32+g)*2], rstd = stats[(b*32+g)*2+1];
        tile[ty + r*8][tx] = (v - mean) * rstd * gamma[c] + beta[c];
    }
    __syncthreads();
    #pragma unroll
    for (int r = 0; r < 4; ++r) {
        int n = nt*32 + ty + r*8;
        int c = ct*32 + tx;
        hT[((size_t)(b * HWS + n)) * CH + c] = (bf16)tile[tx][ty + r*8];
    }
}

// ---------------------------------------------------------------- qkv GEMM + fused V-transpose (round-7)
__global__ __launch_bounds__(256, 3)
void qkv_gemm(const bf16* __restrict__ W, const bf16* __restrict__ hT,
              const float* __restrict__ bias, bf16* __restrict__ qkv,
              bf16* __restrict__ vT) {
    __shared__ __align__(16) bf16 SMEM[128*CPQ];   // 34816 B (staging uses 32 KB)
    bf16* As = SMEM;            // [128 o][64 k] swizzled, pitch 64
    bf16* Bs = SMEM + 8192;     // [128 bn][64 k]
    int bx = blockIdx.x;                 // 12 * 128 = 1536 blocks
    int po = bx >> 7, qo = bx & 127;     // qo low bits -> XCD locality on hT
    int obase = po*128, bnbase = qo*128;
    int tid = threadIdx.x;
    int lane = tid & 63, w = tid >> 6;
    int quad = lane >> 4, l15 = lane & 15;
    int wm = w >> 1, wn = w & 1;
    int x7 = l15 & 7;
    int srow = lane >> 3, spos = lane & 7;          // wave covers 8 rows x 8 chunks
    int sgc = (spos ^ srow) * 8;                    // swizzled source chunk (elements)

    f32x4 acc[4][4] = {};
    for (int k0 = 0; k0 < 512; k0 += 64) {
        #pragma unroll
        for (int r = 0; r < 4; ++r) {
            int rb = r*32 + w*8;                    // row-group base (multiple of 8)
            gload_lds16(W  + ((size_t)(obase  + rb + srow))*512 + k0 + sgc, &As[rb*64]);
            gload_lds16(hT + ((size_t)(bnbase + rb + srow))*512 + k0 + sgc, &Bs[rb*64]);
        }
        __syncthreads();                            // drains vmcnt -> tiles ready
        #pragma unroll
        for (int ks = 0; ks < 2; ++ks) {
            int ch = (ks*4 + quad) ^ x7;
            bf16x8 af[4], bfv[4];
            #pragma unroll
            for (int mt = 0; mt < 4; ++mt)
                af[mt] = *(const bf16x8*)(&As[(wm*64 + mt*16 + l15)*64 + ch*8]);
            #pragma unroll
            for (int nt = 0; nt < 4; ++nt)
                bfv[nt] = *(const bf16x8*)(&Bs[(wn*64 + nt*16 + l15)*64 + ch*8]);
            #pragma unroll
            for (int mt = 0; mt < 4; ++mt)
                #pragma unroll
                for (int nt = 0; nt < 4; ++nt)
                    acc[mt][nt] = __builtin_amdgcn_mfma_f32_16x16x32_bf16(af[mt], bfv[nt], acc[mt][nt], 0, 0, 0);
        }
        __syncthreads();
    }

    // ---- epilogue: bias, V-direct stores, C restage for Q/K (round-4 exact)
    bf16* Cs = SMEM;                 // [128 bn][CPQ]
    int b = bnbase >> 10;
    int nbase = bnbase & 1023;
    #pragma unroll
    for (int mt = 0; mt < 4; ++mt) {
        int o0 = obase + wm*64 + mt*16 + quad*4;
        float4 bb = *(const float4*)(bias + o0);
        int c192 = o0 % 192;
        bool isV = (c192 >= 128);
        int h = o0 / 192;
        int d0 = c192 - 128;
        #pragma unroll
        for (int nt = 0; nt < 4; ++nt) {
            int bn_l = wn*64 + nt*16 + l15;
            bf16x4 v;
            v[0] = (bf16)(acc[mt][nt][0] + bb.x);
            v[1] = (bf16)(acc[mt][nt][1] + bb.y);
            v[2] = (bf16)(acc[mt][nt][2] + bb.z);
            v[3] = (bf16)(acc[mt][nt][3] + bb.w);
            *(bf16x4*)(&Cs[bn_l*CPQ + (o0 - obase)]) = v;
            if (isV) {
                int key = nbase + bn_l;
                size_t vb_ = ((size_t)((b*8 + h)*64 + d0)) * HWS + key;
                vT[vb_]          = v[0];
                vT[vb_ + HWS]    = v[1];
                vT[vb_ + 2*HWS]  = v[2];
                vT[vb_ + 3*HWS]  = v[3];
            }
        }
    }
    __syncthreads();
    #pragma unroll
    for (int p = 0; p < 8; ++p) {
        int bn_l = p*16 + (tid >> 4);
        int o8 = (tid & 15) * 8;
        if ((obase + o8) % 192 < 128) {
            uint4 v = *(const uint4*)(&Cs[bn_l*CPQ + o8]);
            *(uint4*)(qkv + ((size_t)(bnbase + bn_l)) * O3 + obase + o8) = v;
        }
    }
}

// ---------------------------------------------------------------- flash attention (v12)
// v11 with its three measured defects fixed (round-6 counters):
//  1. 8 waves/block, 256 q, grid 512: K/V global re-read back to v7 level
//     (FETCH 40 -> ~25 GB); 2 blocks/CU, 16 waves/CU.
//  2. lane^32 exchange via v_permlane32_swap_b32 (VALU pipe) instead of shfl_xor
//     (ds_bpermute -> was the 4.4M bank-conflict source). Per 32-key block:
//     8 packs + 4 swaps replace 8 shfl + 8 cndmask.
//  3. K/V staging/dbuf/1-barrier-per-kt verbatim from round-2 v7 (verified 50us).
// Layouts (m74/m101-verified): QK z=mfma32(K,Q): D[key=(r&3)+8*(r>>2)+4hi][q=l31];
// PV acc=mfma32(V^T,P): D[d=(r&3)+8*(r>>2)+4hi][q=l31]. P-frag B[k=hi*8+j][q].
// swap(A=w[4kl+t], B=w[4kl+2+t]): A'.hi<-B.lo, B'.lo<-A.hi => frag=[A't0,A't1,B't0,B't1].
__global__ __launch_bounds__(512, 4)
void flash_attn(const bf16* __restrict__ qkv, const bf16* __restrict__ vT,
                bf16* __restrict__ A2) {
    __shared__ __align__(16) bf16 Ks[2][64*64];    // 16 KB
    __shared__ __align__(16) bf16 Vs[2][64*64];    // 16 KB  [d 64][key 64] swizzled
    __shared__ __align__(16) bf16 Ps[8][32*OPD];   // 36 KB, per-wave epilogue staging
    int bx = blockIdx.x;                 // 512: g = bx&127 (XCD locality), qt = bx>>7
    int g = bx & 127, qt = bx >> 7;
    int b = g >> 3, h = g & 7;
    int tid = threadIdx.x, lane = tid & 63, w = tid >> 6;   // w 0..7
    int l31 = lane & 31, hi = lane >> 5;
    int x7l = l31 & 7;
    int srow = lane >> 3, spos = lane & 7;
    int sgc = (spos ^ srow) * 8;         // pre-swizzled source chunk for linear LDS dest
    const float kLog2 = 0.04419417382415922f * 1.44269504088896341f; // 512^-0.5 * log2(e)

    // Q-frags (B operand): Q[q = l31][d = seg*16 + hi*8 + j], pre-scaled
    bf16x8 aq[4];
    {
        int qrow = qt*256 + w*32 + l31;
        const bf16* qb = qkv + ((size_t)(b * HWS + qrow)) * O3 + h*192 + hi*8;
        #pragma unroll
        for (int seg = 0; seg < 4; ++seg) {
            aq[seg] = *(const bf16x8*)(qb + seg*16);
            #pragma unroll
            for (int j = 0; j < 8; ++j)
                aq[seg][j] = (bf16)((float)aq[seg][j] * kLog2);
        }
    }

    // staging (v7 verbatim): wave w covers rows w*8..w*8+7, one DMA each for K and V
    const bf16* kg = qkv + ((size_t)(b*HWS + w*8 + srow))*O3 + h*192 + 64 + sgc;
    const bf16* vg = vT  + ((size_t)(g*DH  + w*8 + srow))*HWS + sgc;

    gload_lds16(kg, &Ks[0][w*512]);
    gload_lds16(vg, &Vs[0][w*512]);

    f32x16 acc[2] = {};                  // D[m=d regs][n=q lane]; db = d/32
    f32x4 L4 = {};                       // lane-local partial row sums (q = l31)
    __syncthreads();                     // drains vmcnt: tile 0 ready

    for (int kt = 0; kt < 16; ++kt) {
        int cur = kt & 1;
        if (kt < 15) {                   // prefetch kt+1 (async DMA)
            gload_lds16(kg + (size_t)((kt+1)*64)*O3, &Ks[cur^1][w*512]);
            gload_lds16(vg + (kt+1)*64,              &Vs[cur^1][w*512]);
        }
        const bf16* Kc = &Ks[cur][0];
        const bf16* Vc = &Vs[cur][0];

        bf16x8 pa[4];                    // P-frags: B[key = ks*16 + hi*8 + j][q = l31]
        #pragma unroll
        for (int kb = 0; kb < 2; ++kb) {
            // S^T block: keys kb*32..+31 x q 0..31 over d=64
            f32x16 z = {};
            #pragma unroll
            for (int seg = 0; seg < 4; ++seg) {
                bf16x8 ak = *(const bf16x8*)(&Kc[(kb*32 + l31)*64 + (((seg*2 + hi) ^ x7l)*8)]);
                z = __builtin_amdgcn_mfma_f32_32x32x16_bf16(ak, aq[seg], z, 0, 0, 0);
            }
            // exp (lane-local: key = kb*32 + (r&3)+8*(r>>2)+4hi for its q)
            float e[16];
            #pragma unroll
            for (int r = 0; r < 16; ++r) {
                e[r] = fast_exp2(z[r]);
                L4[r & 3] += e[r];
            }
            // pack adjacent-key pairs: word i covers keys kb*32 + 8*(i>>1) + 2*(i&1) + 4hi
            unsigned int w8[8];
            #pragma unroll
            for (int i = 0; i < 8; ++i)
                w8[i] = pkbf(e[2*i], e[2*i + 1]);
            // lane^32 half exchange on the VALU pipe (no LDS): 2 swaps per 16-key seg
            #pragma unroll
            for (int kl = 0; kl < 2; ++kl) {
                unsigned int a0 = w8[4*kl + 0], a1 = w8[4*kl + 1];
                unsigned int b0 = w8[4*kl + 2], b1 = w8[4*kl + 3];
                asm("v_permlane32_swap_b32 %0, %1" : "+v"(a0), "+v"(b0));
                asm("v_permlane32_swap_b32 %0, %1" : "+v"(a1), "+v"(b1));
                i32x4 f;
                f[0] = (int)a0; f[1] = (int)a1; f[2] = (int)b0; f[3] = (int)b1;
                pa[kb*2 + kl] = __builtin_bit_cast(bf16x8, f);
            }
        }

        // PV: acc[db] += V^T[d][key] x P[key][q] over 4 key-segs
        #pragma unroll
        for (int db = 0; db < 2; ++db)
            #pragma unroll
            for (int ks = 0; ks < 4; ++ks) {
                bf16x8 av = *(const bf16x8*)(&Vc[(db*32 + l31)*64 + (((ks*2 + hi) ^ x7l)*8)]);
                acc[db] = __builtin_amdgcn_mfma_f32_32x32x16_bf16(av, pa[ks], acc[db], 0, 0, 0);
            }
        __syncthreads();   // all waves done with buf[cur]; prefetch drained
    }

    // row sum: lane-local partials + the other half's keys
    float Lf = (L4[0] + L4[1]) + (L4[2] + L4[3]);
    Lf += __shfl_xor(Lf, 32, 64);
    float Linv = 1.f / Lf;

    // epilogue: acc[db][r] -> out[d = db*32 + (r&3)+8*(r>>2)+4hi][q = l31]
    bf16* Psw = &Ps[w][0];
    #pragma unroll
    for (int db = 0; db < 2; ++db)
        #pragma unroll
        for (int i = 0; i < 8; ++i) {
            int d = db*32 + (i >> 1)*8 + (i & 1)*2 + 4*hi;
            unsigned int wv = pkbf(acc[db][2*i] * Linv, acc[db][2*i + 1] * Linv);
            *(unsigned int*)(&Psw[l31*OPD + d]) = wv;
        }

    int bp = g & 15;          // output batch (reference's head-major quirk)
    int hp = g >> 4;          // output head slot
    #pragma unroll
    for (int cc = 0; cc < 4; ++cc) {
        int idx = cc*64 + lane;
        int q = idx >> 3, dcc = idx & 7;
        uint4 v = *(const uint4*)(&Psw[q*OPD + dcc*8]);
        size_t oidx = ((size_t)(bp * HWS + qt*256 + w*32 + q)) * CH + hp*64 + dcc*8;
        *(uint4*)(A2 + oidx) = v;
    }
}

// ---------------------------------------------------------------- proj GEMM + bias + residual (round-7)
__global__ __launch_bounds__(256, 3)
void proj_gemm(const bf16* __restrict__ A2, const bf16* __restrict__ Wp,
               const float* __restrict__ bias, const float* __restrict__ x,
               float* __restrict__ out) {
    __shared__ __align__(16) bf16 SMEM[16896];     // 33792 B (staging 32 KB)
    bf16* As = SMEM;            // [128 bn][64 k] swizzled, pitch 64
    bf16* Bs = SMEM + 8192;     // [128 o][64 k]
    int bx = blockIdx.x;                 // 512
    int po = bx >> 7, qo = bx & 127;
    int obase = po*128, bnbase = qo*128;
    int tid = threadIdx.x;
    int lane = tid & 63, w = tid >> 6;
    int quad = lane >> 4, l15 = lane & 15;
    int wm = w >> 1, wn = w & 1;
    int x7 = l15 & 7;
    int srow = lane >> 3, spos = lane & 7;
    int sgc = (spos ^ srow) * 8;

    f32x4 acc[4][4] = {};
    for (int k0 = 0; k0 < 512; k0 += 64) {
        #pragma unroll
        for (int r = 0; r < 4; ++r) {
            int rb = r*32 + w*8;
            gload_lds16(A2 + ((size_t)(bnbase + rb + srow))*512 + k0 + sgc, &As[rb*64]);
            gload_lds16(Wp + ((size_t)(obase  + rb + srow))*512 + k0 + sgc, &Bs[rb*64]);
        }
        __syncthreads();
        #pragma unroll
        for (int ks = 0; ks < 2; ++ks) {
            int ch = (ks*4 + quad) ^ x7;
            bf16x8 af[4], bfv[4];
            #pragma unroll
            for (int mt = 0; mt < 4; ++mt)
                af[mt] = *(const bf16x8*)(&As[(wm*64 + mt*16 + l15)*64 + ch*8]);
            #pragma unroll
            for (int nt = 0; nt < 4; ++nt)
                bfv[nt] = *(const bf16x8*)(&Bs[(wn*64 + nt*16 + l15)*64 + ch*8]);
            #pragma unroll
            for (int mt = 0; mt < 4; ++mt)
                #pragma unroll
                for (int nt = 0; nt < 4; ++nt)
                    acc[mt][nt] = __builtin_amdgcn_mfma_f32_16x16x32_bf16(af[mt], bfv[nt], acc[mt][nt], 0, 0, 0);
        }
        __syncthreads();
    }

    // epilogue (round-4 exact): bn = bnbase + wm*64 + mt*16 + quad*4 + r, o = obase + wn*64 + nt*16 + l15
    float* Cf = (float*)SMEM;        // [64 bn][CPF] fp32 per half-pass
    int bb = bnbase >> 10;
    int nbase = bnbase & 1023;
    #pragma unroll
    for (int hh = 0; hh < 2; ++hh) {
        if (wm == hh) {
            #pragma unroll
            for (int mt = 0; mt < 4; ++mt)
                #pragma unroll
                for (int nt = 0; nt < 4; ++nt)
                    #pragma unroll
                    for (int r = 0; r < 4; ++r)
                        Cf[(mt*16 + quad*4 + r)*CPF + wn*64 + nt*16 + l15] = acc[mt][nt][r];
        }
        __syncthreads();
        #pragma unroll
        for (int p = 0; p < 4; ++p) {
            int ol = p*32 + (tid >> 3);
            int nl0 = (tid & 7) * 8;
            int o = obase + ol;
            float bv = bias[o];
            #pragma unroll
            for (int jj = 0; jj < 2; ++jj) {
                int nl = nl0 + jj*4;
                size_t idx = ((size_t)(bb * CH + o)) * HWS + nbase + hh*64 + nl;
                float4 xr = *(const float4*)(x + idx);
                float4 res;
                res.x = Cf[(nl+0)*CPF + ol] + bv + xr.x;
                res.y = Cf[(nl+1)*CPF + ol] + bv + xr.y;
                res.z = Cf[(nl+2)*CPF + ol] + bv + xr.z;
                res.w = Cf[(nl+3)*CPF + ol] + bv + xr.w;
                *(float4*)(out + idx) = res;
            }
        }
        __syncthreads();
    }
}

// ---------------------------------------------------------------- launch
extern "C" void kernel_launch(void* const* d_in, const int* in_sizes, int n_in,
                              void* d_out, int out_size, void* d_ws, size_t ws_size,
                              hipStream_t stream) {
    const float* x      = (const float*)d_in[0];
    const float* gamma  = (const float*)d_in[1];
    const float* beta   = (const float*)d_in[2];
    const float* w_qkv  = (const float*)d_in[3];
    const float* b_qkv  = (const float*)d_in[4];
    const float* w_proj = (const float*)d_in[5];
    const float* b_proj = (const float*)d_in[6];
    float* out = (float*)d_out;

    char* ws = (char*)d_ws;
    float* stats = (float*)(ws + 0);                       //   4 KB
    bf16*  wq_b  = (bf16*)(ws + 4096);                     // 1.5 MB
    bf16*  wp_b  = (bf16*)(ws + 1576960);                  // 0.5 MB
    bf16*  hT    = (bf16*)(ws + 2101248);                  // 16 MB (aliased by A2 later)
    bf16*  qkv   = (bf16*)(ws + 18878464);                 // 48 MB (V slots unused)
    bf16*  vT    = (bf16*)(ws + 69210112);                 // 16 MB
    bf16*  A2    = hT;                                     // reuse: hT dead after qkv_gemm

    prep       <<<4608, 256, 0, stream>>>(x, stats, w_qkv, w_proj, wq_b, wp_b);
    gn_apply_t <<<8192, 256, 0, stream>>>(x, stats, gamma, beta, hT);
    qkv_gemm   <<<1536, 256, 0, stream>>>(wq_b, hT, b_qkv, qkv, vT);
    flash_attn <<<512,  512, 0, stream>>>(qkv, vT, A2);
    proj_gemm  <<<512,  256, 0, stream>>>(A2, wp_b, b_proj, x, out);
}